// Round 5
// baseline (519.683 us; speedup 1.0000x reference)
//
#include <hip/hip_runtime.h>
#include <math.h>

typedef short s16x8 __attribute__((ext_vector_type(8)));
typedef __bf16 b16x8 __attribute__((ext_vector_type(8)));
typedef float f32x4 __attribute__((ext_vector_type(4)));
typedef unsigned int u32x4 __attribute__((ext_vector_type(4)));

__device__ inline short f2bf(float f) {
    unsigned u = __float_as_uint(f);
    unsigned r = u + 0x7FFFu + ((u >> 16) & 1u);   // RNE
    return (short)(r >> 16);
}
__device__ inline float bf2f(unsigned short u) {
    return __uint_as_float(((unsigned)u) << 16);
}

// async global->LDS, 16B per lane; lds dest = wave-uniform base + lane*16
#define GLDS16(g, l)                                                            \
    __builtin_amdgcn_global_load_lds(                                           \
        (const __attribute__((address_space(1))) void*)(g),                     \
        (__attribute__((address_space(3))) void*)(l), 16, 0, 0)

// ---------------- CSR build ----------------

__global__ void init_cnt_kernel(int* cnt, int n) {
    int i = blockIdx.x * blockDim.x + threadIdx.x;
    if (i < n) cnt[i] = 0;
}

__global__ void count_kernel(const int* __restrict__ dst, int* __restrict__ cnt, int E) {
    int e = blockIdx.x * blockDim.x + threadIdx.x;
    if (e < E) atomicAdd(&cnt[dst[e]], 1);
}

__global__ __launch_bounds__(1024) void blockscan_kernel(const int* __restrict__ cnt,
                                                         int* __restrict__ rp,
                                                         int* __restrict__ bsum, int n) {
    __shared__ int sdata[1024];
    int tid = threadIdx.x;
    int i = blockIdx.x * 1024 + tid;
    int v = (i < n) ? cnt[i] : 0;
    sdata[tid] = v;
    __syncthreads();
    for (int off = 1; off < 1024; off <<= 1) {
        int t = 0;
        if (tid >= off) t = sdata[tid - off];
        __syncthreads();
        sdata[tid] += t;
        __syncthreads();
    }
    if (i < n) rp[i] = sdata[tid] - v;       // local exclusive
    if (tid == 1023) bsum[blockIdx.x] = sdata[1023];
}

__global__ void topscan_kernel(int* bsum, int nb) {
    int lane = threadIdx.x;                   // 64 threads
    int carry = 0;
    for (int base = 0; base < nb; base += 64) {
        int idx = base + lane;
        int orig = (idx < nb) ? bsum[idx] : 0;
        int v = orig;
        for (int off = 1; off < 64; off <<= 1) {
            int t = __shfl_up(v, off, 64);
            if (lane >= off) v += t;
        }
        if (idx < nb) bsum[idx] = carry + v - orig;   // exclusive
        carry += __shfl(v, 63, 64);
    }
}

__global__ __launch_bounds__(1024) void fixup_kernel(int* __restrict__ rp,
                                                     const int* __restrict__ bsum,
                                                     const int* __restrict__ cnt,
                                                     int* __restrict__ cursor,
                                                     float* __restrict__ dinv,
                                                     int n, int E) {
    int i = blockIdx.x * 1024 + threadIdx.x;
    if (i < n) {
        int r = rp[i] + bsum[blockIdx.x];
        rp[i] = r;
        cursor[i] = r;
        dinv[i] = rsqrtf((float)cnt[i] + 1.0f);
    }
    if (i == 0) rp[n] = E;
}

__global__ void fill_kernel(const int* __restrict__ src, const int* __restrict__ dst,
                            int* __restrict__ cursor, const float* __restrict__ dinv,
                            int* __restrict__ csrc, float* __restrict__ cw, int E) {
    int e = blockIdx.x * blockDim.x + threadIdx.x;
    if (e >= E) return;
    int d = dst[e];
    int s = src[e];
    int p = atomicAdd(&cursor[d], 1);
    csrc[p] = s;
    cw[p] = dinv[s] * dinv[d];
}

// ---------------- weight pre-transpose to fragment-ready bf16 ----------------
// Wt chunk layout: [c = k0/32][b = n0/128][nt 0..7][lane 0..63][j 0..7]
//   value = W[c*32 + (lane>>4)*8 + j][b*128 + nt*16 + (lane&15)]

__global__ void make_wt_kernel(const float* __restrict__ W, short* __restrict__ Wt,
                               int K, int N) {
    int idx = blockIdx.x * blockDim.x + threadIdx.x;
    if (idx >= K * N) return;
    int NB = N >> 7;
    int j = idx & 7;
    int l = (idx >> 3) & 63;
    int nt = (idx >> 9) & 7;
    int rest = idx >> 12;
    int b = rest % NB;
    int c = rest / NB;
    int k = c * 32 + (l >> 4) * 8 + j;
    int n = b * 128 + nt * 16 + (l & 15);
    Wt[idx] = f2bf(W[(size_t)k * N + n]);
}

// ---------------- GEMM1: Cb[MxN](bf16) = A_fp32[MxK] @ Wt(bf16 frag-ready) ----------------
// 128x128 block tile, 256 threads = 4 waves, wave tile 64x64 (4x4 of 16x16x32).
// A staged RAW FP32 into LDS via global_load_lds; fp32->bf16 TRUNCATION during frag load.
// Double-buffered LDS (48 KB), one barrier per K-chunk (m97 structure).

__global__ __launch_bounds__(256, 3) void gemm1_kernel(const float* __restrict__ A,
                                                       const short* __restrict__ Wt,
                                                       unsigned short* __restrict__ Cb,
                                                       int M, int N, int K) {
    __shared__ float Afp[2][16 * 256];    // 16 tiles x 64 slots x 16B  (16 KB per buf)
    __shared__ s16x8 Bs[2][8 * 64];       // 8 tiles x 64 slots x 16B   (8 KB per buf)

    const int tid = threadIdx.x;
    const int lane = tid & 63;
    const int wave = tid >> 6;
    const int wm = wave & 1;
    const int wn = wave >> 1;
    const int m0 = blockIdx.y * 128;
    const int n0 = blockIdx.x * 128;
    const int NB = N >> 7;
    const int KC = K >> 5;
    const s16x8* wt = (const s16x8*)Wt;

    f32x4 acc[4][4];
#pragma unroll
    for (int i = 0; i < 4; ++i)
#pragma unroll
        for (int j = 0; j < 4; ++j)
            acc[i][j] = (f32x4){0.f, 0.f, 0.f, 0.f};

    // staging lane geometry (constant across chunks)
    int arow[4];
#pragma unroll
    for (int i = 0; i < 4; ++i) {
        int t = wave * 4 + i;                 // A tile 0..15 : t = mt*2 + h
        int mt = t >> 1;
        int row = m0 + mt * 16 + (lane & 15);
        arow[i] = (row < M) ? row : (M - 1);  // clamp; garbage rows never stored
    }

    auto issue = [&](int c, int buf) {
        const int k0 = c << 5;
#pragma unroll
        for (int i = 0; i < 4; ++i) {
            int t = wave * 4 + i;
            int h = t & 1;
            const float* g = A + (size_t)arow[i] * K + k0 + h * 16 + ((lane >> 4) << 2);
            GLDS16(g, &Afp[buf][t * 256]);
        }
#pragma unroll
        for (int i = 0; i < 2; ++i) {
            int t = wave * 2 + i;
            const s16x8* g = wt + (size_t)(c * NB + blockIdx.x) * 512 + t * 64 + lane;
            GLDS16(g, &Bs[buf][t * 64]);
        }
    };

    issue(0, 0);
    __syncthreads();

    const int q = lane >> 4;            // 0..3 (k-octet of the frag)
    const int hh = q >> 1;              // which 16-k half-tile
    const int qq = (q & 1) << 1;        // starting k-quad within half
    const int ml = lane & 15;

    for (int c = 0; c < KC; ++c) {
        const int cur = c & 1;
        if (c + 1 < KC) issue(c + 1, cur ^ 1);

        b16x8 areg[4], breg[4];
#pragma unroll
        for (int i = 0; i < 4; ++i) {
            int mt = wm * 4 + i;
            const float4* tb = (const float4*)&Afp[cur][(mt * 2 + hh) * 256];
            float4 f0 = tb[qq * 16 + ml];
            float4 f1 = tb[(qq + 1) * 16 + ml];
            u32x4 p;
            p.x = (__float_as_uint(f0.x) >> 16) | (__float_as_uint(f0.y) & 0xFFFF0000u);
            p.y = (__float_as_uint(f0.z) >> 16) | (__float_as_uint(f0.w) & 0xFFFF0000u);
            p.z = (__float_as_uint(f1.x) >> 16) | (__float_as_uint(f1.y) & 0xFFFF0000u);
            p.w = (__float_as_uint(f1.z) >> 16) | (__float_as_uint(f1.w) & 0xFFFF0000u);
            areg[i] = __builtin_bit_cast(b16x8, p);
        }
#pragma unroll
        for (int j = 0; j < 4; ++j)
            breg[j] = __builtin_bit_cast(b16x8, Bs[cur][(wn * 4 + j) * 64 + lane]);
#pragma unroll
        for (int i = 0; i < 4; ++i)
#pragma unroll
            for (int j = 0; j < 4; ++j)
                acc[i][j] = __builtin_amdgcn_mfma_f32_16x16x32_bf16(areg[i], breg[j], acc[i][j], 0, 0, 0);
        __syncthreads();
    }

    const int quad = lane >> 4;
    const int nl = lane & 15;
#pragma unroll
    for (int i = 0; i < 4; ++i) {
        int rbase = m0 + wm * 64 + i * 16 + quad * 4;
#pragma unroll
        for (int j = 0; j < 4; ++j) {
            int col = n0 + wn * 64 + j * 16 + nl;
#pragma unroll
            for (int r = 0; r < 4; ++r) {
                int row = rbase + r;
                if (row < M) Cb[(size_t)row * N + col] = (unsigned short)f2bf(acc[i][j][r]);
            }
        }
    }
}

// ---------------- GEMM2: Cb[Mx128](bf16) = A_bf16[MxK] @ Wt(frag-ready) ----------------
// 64x128 block tile (grid 782), 4 waves, wave tile 32x64 (2x4). A lands frag-ready via
// per-lane gptr. Double-buffered (24 KB), one barrier per chunk.

__global__ __launch_bounds__(256, 3) void gemm2_kernel(const unsigned short* __restrict__ A,
                                                       const short* __restrict__ Wt,
                                                       unsigned short* __restrict__ Cb,
                                                       int M, int N, int K) {
    __shared__ s16x8 As[2][4 * 64];       // 4 KB per buf
    __shared__ s16x8 Bs[2][8 * 64];       // 8 KB per buf

    const int tid = threadIdx.x;
    const int lane = tid & 63;
    const int wave = tid >> 6;
    const int wm = wave & 1;
    const int wn = wave >> 1;
    const int m0 = blockIdx.y * 64;
    const int NB = N >> 7;
    const int KC = K >> 5;
    const s16x8* wt = (const s16x8*)Wt;
    const s16x8* ap = (const s16x8*)A;

    f32x4 acc[2][4];
#pragma unroll
    for (int i = 0; i < 2; ++i)
#pragma unroll
        for (int j = 0; j < 4; ++j)
            acc[i][j] = (f32x4){0.f, 0.f, 0.f, 0.f};

    int row = m0 + wave * 16 + (lane & 15);
    if (row >= M) row = M - 1;
    const int kq = (lane >> 4);           // k-octet index (x8 elems = 1 s16x8)

    auto issue = [&](int c, int buf) {
#pragma unroll
        for (int i = 0; i < 1; ++i) {
            const s16x8* g = ap + ((size_t)row * K + (c << 5)) / 8 + kq;
            GLDS16(g, &As[buf][wave * 64]);
        }
#pragma unroll
        for (int i = 0; i < 2; ++i) {
            int t = wave * 2 + i;
            const s16x8* g = wt + (size_t)(c * NB + blockIdx.x) * 512 + t * 64 + lane;
            GLDS16(g, &Bs[buf][t * 64]);
        }
    };

    issue(0, 0);
    __syncthreads();

    for (int c = 0; c < KC; ++c) {
        const int cur = c & 1;
        if (c + 1 < KC) issue(c + 1, cur ^ 1);

        b16x8 areg[2], breg[4];
#pragma unroll
        for (int i = 0; i < 2; ++i)
            areg[i] = __builtin_bit_cast(b16x8, As[cur][(wm * 2 + i) * 64 + lane]);
#pragma unroll
        for (int j = 0; j < 4; ++j)
            breg[j] = __builtin_bit_cast(b16x8, Bs[cur][(wn * 4 + j) * 64 + lane]);
#pragma unroll
        for (int i = 0; i < 2; ++i)
#pragma unroll
            for (int j = 0; j < 4; ++j)
                acc[i][j] = __builtin_amdgcn_mfma_f32_16x16x32_bf16(areg[i], breg[j], acc[i][j], 0, 0, 0);
        __syncthreads();
    }

    const int quad = lane >> 4;
    const int nl = lane & 15;
#pragma unroll
    for (int i = 0; i < 2; ++i) {
        int rbase = m0 + wm * 32 + i * 16 + quad * 4;
#pragma unroll
        for (int j = 0; j < 4; ++j) {
            int col = wn * 64 + j * 16 + nl;
#pragma unroll
            for (int r = 0; r < 4; ++r) {
                int rr = rbase + r;
                if (rr < M) Cb[(size_t)rr * N + col] = (unsigned short)f2bf(acc[i][j][r]);
            }
        }
    }
}

// ---------------- aggregation, bf16 in ----------------

__global__ __launch_bounds__(256) void agg256_kernel(const unsigned short* __restrict__ h,
                                                     const int* __restrict__ rp,
                                                     const int* __restrict__ csrc,
                                                     const float* __restrict__ cw,
                                                     const float* __restrict__ dinv,
                                                     const float* __restrict__ bias,
                                                     unsigned short* __restrict__ out, int n) {
    int node = blockIdx.x * 4 + (threadIdx.x >> 6);
    int lane = threadIdx.x & 63;
    if (node >= n) return;
    const ushort4* hp = (const ushort4*)h;       // 64 per row
    float di = dinv[node];
    float ws = di * di;
    ushort4 sv = hp[(size_t)node * 64 + lane];
    float a0 = ws * bf2f(sv.x), a1 = ws * bf2f(sv.y), a2 = ws * bf2f(sv.z), a3 = ws * bf2f(sv.w);
    int e = rp[node], e1 = rp[node + 1];
    for (; e + 1 < e1; e += 2) {
        int s0 = csrc[e], s1 = csrc[e + 1];
        float w0 = cw[e], w1 = cw[e + 1];
        ushort4 v0 = hp[(size_t)s0 * 64 + lane];
        ushort4 v1 = hp[(size_t)s1 * 64 + lane];
        a0 += w0 * bf2f(v0.x) + w1 * bf2f(v1.x);
        a1 += w0 * bf2f(v0.y) + w1 * bf2f(v1.y);
        a2 += w0 * bf2f(v0.z) + w1 * bf2f(v1.z);
        a3 += w0 * bf2f(v0.w) + w1 * bf2f(v1.w);
    }
    if (e < e1) {
        int s0 = csrc[e];
        float w0 = cw[e];
        ushort4 v0 = hp[(size_t)s0 * 64 + lane];
        a0 += w0 * bf2f(v0.x); a1 += w0 * bf2f(v0.y);
        a2 += w0 * bf2f(v0.z); a3 += w0 * bf2f(v0.w);
    }
    float4 bv = *(const float4*)&bias[lane * 4];
    a0 = fmaxf(a0 + bv.x, 0.f); a1 = fmaxf(a1 + bv.y, 0.f);
    a2 = fmaxf(a2 + bv.z, 0.f); a3 = fmaxf(a3 + bv.w, 0.f);
    ushort4 ov;
    ov.x = (unsigned short)f2bf(a0); ov.y = (unsigned short)f2bf(a1);
    ov.z = (unsigned short)f2bf(a2); ov.w = (unsigned short)f2bf(a3);
    ((ushort4*)out)[(size_t)node * 64 + lane] = ov;
}

__global__ __launch_bounds__(256) void agg128_w3_kernel(const unsigned short* __restrict__ h,
                                                        const int* __restrict__ rp,
                                                        const int* __restrict__ csrc,
                                                        const float* __restrict__ cw,
                                                        const float* __restrict__ dinv,
                                                        const float* __restrict__ b2,
                                                        const float* __restrict__ W3,
                                                        float* __restrict__ z, int n) {
    int node = blockIdx.x * 4 + (threadIdx.x >> 6);
    int lane = threadIdx.x & 63;
    if (node >= n) return;
    const unsigned* hp = (const unsigned*)h;     // 64 uints per row (2 bf16 each)
    float di = dinv[node];
    float ws = di * di;
    unsigned sv = hp[(size_t)node * 64 + lane];
    float a0 = ws * __uint_as_float(sv << 16);
    float a1 = ws * __uint_as_float(sv & 0xFFFF0000u);
    int e = rp[node], e1 = rp[node + 1];
    for (; e + 1 < e1; e += 2) {
        int s0 = csrc[e], s1 = csrc[e + 1];
        float w0 = cw[e], w1 = cw[e + 1];
        unsigned v0 = hp[(size_t)s0 * 64 + lane];
        unsigned v1 = hp[(size_t)s1 * 64 + lane];
        a0 += w0 * __uint_as_float(v0 << 16) + w1 * __uint_as_float(v1 << 16);
        a1 += w0 * __uint_as_float(v0 & 0xFFFF0000u) + w1 * __uint_as_float(v1 & 0xFFFF0000u);
    }
    if (e < e1) {
        int s0 = csrc[e];
        float w0 = cw[e];
        unsigned v0 = hp[(size_t)s0 * 64 + lane];
        a0 += w0 * __uint_as_float(v0 << 16);
        a1 += w0 * __uint_as_float(v0 & 0xFFFF0000u);
    }
    float2 bv = *(const float2*)&b2[lane * 2];
    a0 = fmaxf(a0 + bv.x, 0.f);
    a1 = fmaxf(a1 + bv.y, 0.f);
    float4 wv = *(const float4*)&W3[lane * 4];
    float z0 = a0 * wv.x + a1 * wv.z;
    float z1 = a0 * wv.y + a1 * wv.w;
    for (int off = 32; off > 0; off >>= 1) {
        z0 += __shfl_down(z0, off, 64);
        z1 += __shfl_down(z1, off, 64);
    }
    if (lane == 0) {
        z[2 * (size_t)node] = z0;
        z[2 * (size_t)node + 1] = z1;
    }
}

__global__ void agg3_kernel(const float* __restrict__ z, const int* __restrict__ rp,
                            const int* __restrict__ csrc, const float* __restrict__ cw,
                            const float* __restrict__ dinv, const float* __restrict__ bias,
                            float* __restrict__ out, int n) {
    int node = blockIdx.x * blockDim.x + threadIdx.x;
    if (node >= n) return;
    float di = dinv[node];
    float a0 = di * di * z[2 * (size_t)node];
    float a1 = di * di * z[2 * (size_t)node + 1];
    int e1 = rp[node + 1];
    for (int e = rp[node]; e < e1; ++e) {
        int s = csrc[e];
        float w = cw[e];
        a0 += w * z[2 * (size_t)s];
        a1 += w * z[2 * (size_t)s + 1];
    }
    a0 += bias[0];
    a1 += bias[1];
    out[2 * (size_t)node]     = 1.f / (1.f + __expf(-a0));
    out[2 * (size_t)node + 1] = 1.f / (1.f + __expf(-a1));
}

// ---------------- launch ----------------

extern "C" void kernel_launch(void* const* d_in, const int* in_sizes, int n_in,
                              void* d_out, int out_size, void* d_ws, size_t ws_size,
                              hipStream_t stream) {
    const float* x  = (const float*)d_in[0];
    const int*   ei = (const int*)d_in[1];
    const float* W1 = (const float*)d_in[2];
    const float* b1 = (const float*)d_in[3];
    const float* W2 = (const float*)d_in[4];
    const float* b2 = (const float*)d_in[5];
    const float* W3 = (const float*)d_in[6];
    const float* b3 = (const float*)d_in[7];
    float* out = (float*)d_out;

    const int E  = in_sizes[1] / 2;
    const int C1 = in_sizes[3];              // 256
    const int C2 = in_sizes[5];              // 128
    const int K1 = in_sizes[2] / C1;         // 768
    const int N  = in_sizes[0] / K1;         // 50000

    const int* srcv = ei;
    const int* dstv = ei + E;

    char* p = (char*)d_ws;
    auto carve = [&](size_t bytes) {
        char* r = p;
        p += (bytes + 255) & ~(size_t)255;
        return r;
    };
    int*   cnt    = (int*)carve((size_t)N * 4);
    int*   rp     = (int*)carve((size_t)(N + 1) * 4);
    int*   cursor = (int*)carve((size_t)N * 4);
    float* dinv   = (float*)carve((size_t)N * 4);
    int*   bsum   = (int*)carve(1024 * 4);
    int*   csrc   = (int*)carve((size_t)E * 4);
    float* cw     = (float*)carve((size_t)E * 4);
    short* Wt1    = (short*)carve((size_t)K1 * C1 * 2);
    short* Wt2    = (short*)carve((size_t)C1 * C2 * 2);
    unsigned short* hA = (unsigned short*)carve((size_t)N * C1 * 2);
    unsigned short* hB = (unsigned short*)carve((size_t)N * C1 * 2);
    float* zbuf   = (float*)carve((size_t)N * 2 * 4);

    const int nb = (N + 1023) / 1024;

    // CSR build
    init_cnt_kernel<<<(N + 255) / 256, 256, 0, stream>>>(cnt, N);
    count_kernel<<<(E + 255) / 256, 256, 0, stream>>>(dstv, cnt, E);
    blockscan_kernel<<<nb, 1024, 0, stream>>>(cnt, rp, bsum, N);
    topscan_kernel<<<1, 64, 0, stream>>>(bsum, nb);
    fixup_kernel<<<nb, 1024, 0, stream>>>(rp, bsum, cnt, cursor, dinv, N, E);
    fill_kernel<<<(E + 255) / 256, 256, 0, stream>>>(srcv, dstv, cursor, dinv, csrc, cw, E);

    // Weight pre-transpose (fragment-ready bf16)
    make_wt_kernel<<<(K1 * C1 + 255) / 256, 256, 0, stream>>>(W1, Wt1, K1, C1);
    make_wt_kernel<<<(C1 * C2 + 255) / 256, 256, 0, stream>>>(W2, Wt2, C1, C2);

    // Layer 1: h1 = x @ W1 ; a1 = relu(Ahat h1 + b1)
    dim3 g1(C1 / 128, (N + 127) / 128);
    gemm1_kernel<<<g1, 256, 0, stream>>>(x, Wt1, hA, N, C1, K1);
    agg256_kernel<<<(N + 3) / 4, 256, 0, stream>>>(hA, rp, csrc, cw, dinv, b1, hB, N);

    // Layer 2: h2 = a1 @ W2 ; fused a2 = relu(Ahat h2 + b2), z = a2 @ W3
    dim3 g2(C2 / 128, (N + 63) / 64);
    gemm2_kernel<<<g2, 256, 0, stream>>>(hB, Wt2, hA, N, C2, C1);
    agg128_w3_kernel<<<(N + 3) / 4, 256, 0, stream>>>(hA, rp, csrc, cw, dinv, b2, W3, zbuf, N);

    // Layer 3 aggregation + sigmoid
    agg3_kernel<<<(N + 255) / 256, 256, 0, stream>>>(zbuf, rp, csrc, cw, dinv, b3, out, N);
}